// Round 14
// baseline (58.388 us; speedup 1.0000x reference)
//
#include <hip/hip_runtime.h>
#include <hip/hip_bf16.h>

#define B_    4096
#define D_    512         // elements = bytes per row (i8)
#define TB_   8192        // 2B rows
#define BM    128
#define BK    128         // 128 B per row per K-tile (0-conflict geometry)
#define NK    4           // D_/BK
#define NTILE 64          // TB_/BM
#define NTRI  2080        // NTILE*(NTILE+1)/2 = 8*260 (XCD-bijective)
#define INV_T 14.285714285714286f   // 1/0.07
#define SCL   (INV_T / 16129.0f)    // 1/(0.07*127*127)
#define SCL2  (SCL * 1.4426950408889634f)   // SCL*log2(e) for exp2

typedef __attribute__((ext_vector_type(4))) int v4i;

#define GLOAD_LDS16(gp, lp)                                                        \
  __builtin_amdgcn_global_load_lds((const __attribute__((address_space(1))) void*)(gp), \
                                   (__attribute__((address_space(3))) void*)(lp),  \
                                   16, 0, 0)

// ---------------------------------------------------------------------------
// Kernel 1: concat + quantize fp32 -> int8 (E8[8192][512], q = rn(127 x)).
// ---------------------------------------------------------------------------
__global__ void ntx_prep(const float* __restrict__ a, const float* __restrict__ b,
                         char* __restrict__ E8) {
  int t = blockIdx.x * blockDim.x + threadIdx.x;      // 0..262143
  int i = t * 16;
  const float* src = (i < B_ * D_) ? (a + i) : (b + (i - B_ * D_));
  v4i o;
#pragma unroll
  for (int g = 0; g < 4; ++g) {
    float4 v = ((const float4*)src)[g];
    int q0 = __float2int_rn(v.x * 127.0f) & 255;
    int q1 = __float2int_rn(v.y * 127.0f) & 255;
    int q2 = __float2int_rn(v.z * 127.0f) & 255;
    int q3 = __float2int_rn(v.w * 127.0f) & 255;
    o[g] = q0 | (q1 << 8) | (q2 << 16) | (q3 << 24);
  }
  ((v4i*)E8)[t] = o;
}

// ---------------------------------------------------------------------------
// Kernel 2: 16-WAVE (1024-thread) blocks. 128x128 i8 tile, BK=128, 4x4 wave
// grid (32x32 per wave, acc 2x2 = 16 AGPR). Routes around the observed
// 2-blocks/CU cap: 16 waves/CU minimum (2x R13), 32 if 2 blocks co-reside.
// Staging: 1024 chunks(16B)/matrix = exactly 1 A + 1 B chunk per thread;
// chunk-XOR swizzle (chunk ^= row&7) on BOTH source and ds_read (0-conflict).
// Epilogue: per-wave row/col partials -> cross-wave LDS reduce (reusing
// As/Bs after the K-loop) -> single-writer P[ti][tj][128] stores (2 MB).
// Triangular tiles; off-diag stores mirror col-sums; pos tiles tj==ti+32.
// ---------------------------------------------------------------------------
__global__ __launch_bounds__(1024, 4)
void ntx_sim(const char* __restrict__ E8, float* __restrict__ P,
             float* __restrict__ pos) {
  __shared__ __align__(16) char As[BM * BK];   // 16 KB
  __shared__ __align__(16) char Bs[BM * BK];   // 16 KB

  // XCD-contiguous bijective swizzle (2080 = 8*260)
  const int bid = blockIdx.x;
  const int t   = (bid & 7) * (NTRI / 8) + (bid >> 3);
  // decode triangular index t -> (ti, tj), ti<=tj
  int ti = (int)((129.0f - sqrtf(16641.0f - 8.0f * (float)t)) * 0.5f);
  while (ti * (129 - ti) / 2 > t) --ti;
  while ((ti + 1) * (128 - ti) / 2 <= t) ++ti;
  const int tj = ti + (t - ti * (129 - ti) / 2);
  const int rowTile = ti * BM, colTile = tj * BM;
  const bool diag = (ti == tj);
  const bool posT = (tj == ti + B_ / BM);   // holds s[r][r+B] on local diag

  const int tid = threadIdx.x, lane = tid & 63, wave = tid >> 6;
  const int wr = wave >> 2;          // 0..3: 32-row band
  const int wc = wave & 3;           // 0..3: 32-col band
  const int llo = lane & 15, lhi = lane >> 4;

  // staging: tile = 128 rows x 8 chunks(16B) = 1024 chunks; 1/thread.
  // source pre-swizzled (chunk ^= row&7), LDS linear (both-sides rule #21)
  const int ch = tid, srow = ch >> 3;
  const int sc = ((ch & 7) ^ (srow & 7)) << 4;
  const unsigned offA  = (unsigned)(rowTile + srow) * D_ + sc;
  const unsigned offB  = (unsigned)(colTile + srow) * D_ + sc;
  const unsigned ldsOf = (unsigned)ch * 16;

  // fragment byte-offsets (same involution on read); 16 B per lane per ks
  unsigned fA[2][2], fB[2][2];
#pragma unroll
  for (int ks = 0; ks < 2; ++ks)
#pragma unroll
    for (int m = 0; m < 2; ++m) {
      int chc = ks * 4 + lhi;
      int ra  = wr * 32 + m * 16 + llo;
      fA[ks][m] = (unsigned)(ra * BK + (((unsigned)chc ^ (ra & 7)) << 4));
      int rb  = wc * 32 + m * 16 + llo;
      fB[ks][m] = (unsigned)(rb * BK + (((unsigned)chc ^ (rb & 7)) << 4));
    }

  v4i acc[2][2] = {};

  for (int kt = 0; kt < NK; ++kt) {
    const unsigned kb = (unsigned)kt * BK;
    GLOAD_LDS16(E8 + offA + kb, &As[ldsOf]);
    GLOAD_LDS16(E8 + offB + kb, &Bs[ldsOf]);
    __syncthreads();   // drains vmcnt: tile resident
#pragma unroll
    for (int ks = 0; ks < 2; ++ks) {
      v4i af[2], bf[2];
#pragma unroll
      for (int m = 0; m < 2; ++m) {
        af[m] = *(const v4i*)&As[fA[ks][m]];
        bf[m] = *(const v4i*)&Bs[fB[ks][m]];
      }
#pragma unroll
      for (int m = 0; m < 2; ++m)
#pragma unroll
        for (int n = 0; n < 2; ++n)
          acc[m][n] = __builtin_amdgcn_mfma_i32_16x16x64_i8(af[m], bf[n],
                                                            acc[m][n], 0, 0, 0);
    }
    __syncthreads();   // protect LDS before next staging (last iter: frees LDS)
  }

  // --- epilogue: exp2, per-wave partials, cross-wave LDS reduce ---
  // C/D layout: col = lane&15, row = (lane>>4)*4 + reg
  float* Rbuf = (float*)As;   // [4 wc][128 rows] = 2 KB (LDS reuse, post-loop)
  float* Cbuf = (float*)Bs;   // [4 wr][128 cols] = 2 KB
  float cs[2] = {0.f, 0.f};
#pragma unroll
  for (int m = 0; m < 2; ++m) {
    float rs[4] = {0.f, 0.f, 0.f, 0.f};
#pragma unroll
    for (int n = 0; n < 2; ++n) {
      int gc = colTile + wc * 32 + n * 16 + llo;
#pragma unroll
      for (int jj = 0; jj < 4; ++jj) {
        int gr = rowTile + wr * 32 + m * 16 + lhi * 4 + jj;
        float si = (float)acc[m][n][jj];
        if (posT && gc - gr == B_) pos[gr] = si * SCL;   // unique writer
        float e = exp2f(si * SCL2);
        e = (diag && gr == gc) ? 0.0f : e;
        rs[jj] += e;
        cs[n]  += e;
      }
    }
#pragma unroll
    for (int jj = 0; jj < 4; ++jj) {
      float v = rs[jj];
      v += __shfl_xor(v, 1);
      v += __shfl_xor(v, 2);
      v += __shfl_xor(v, 4);
      v += __shfl_xor(v, 8);
      if (llo == 0) Rbuf[wc * 128 + wr * 32 + m * 16 + lhi * 4 + jj] = v;
    }
  }
#pragma unroll
  for (int n = 0; n < 2; ++n) {
    float v = cs[n];
    v += __shfl_xor(v, 16);
    v += __shfl_xor(v, 32);
    if (lhi == 0) Cbuf[wr * 128 + wc * 32 + n * 16 + llo] = v;
  }
  __syncthreads();
  if (tid < 128) {
    float v = Rbuf[tid] + Rbuf[128 + tid] + Rbuf[256 + tid] + Rbuf[384 + tid];
    P[((size_t)ti * NTILE + tj) * BM + tid] = v;          // one writer/slot
  } else if (tid < 256) {
    if (!diag) {
      int c = tid - 128;
      float v = Cbuf[c] + Cbuf[128 + c] + Cbuf[256 + c] + Cbuf[384 + c];
      P[((size_t)tj * NTILE + ti) * BM + c] = v;          // mirror slot
    }
  }
}

// ---------------------------------------------------------------------------
// Kernel 3: gather L[r] = sum_j P[ti][j][rloc]; nll = log(L) - pos;
// per-block partial -> par[32].
// ---------------------------------------------------------------------------
__global__ void ntx_fin1(const float* __restrict__ P, const float* __restrict__ pos,
                         float* __restrict__ par) {
  int r = blockIdx.x * 256 + threadIdx.x;     // 32 blocks x 256 rows
  int ti = r >> 7, rloc = r & 127;
  const float* base = P + (size_t)ti * NTILE * BM + rloc;
  float s = 0.f;
#pragma unroll 16
  for (int j = 0; j < NTILE; ++j) s += base[j * BM];
  float nll = __logf(s) - pos[r & (B_ - 1)];
  float v = nll;
#pragma unroll
  for (int off = 1; off < 64; off <<= 1) v += __shfl_xor(v, off);
  __shared__ float sm[4];
  if ((threadIdx.x & 63) == 0) sm[threadIdx.x >> 6] = v;
  __syncthreads();
  if (threadIdx.x == 0) par[blockIdx.x] = sm[0] + sm[1] + sm[2] + sm[3];
}

// Kernel 4: fold 32 partials -> mean
__global__ void ntx_fin2(const float* __restrict__ par, float* __restrict__ out) {
  int t = threadIdx.x;                         // 64 threads
  float s = (t < 32) ? par[t] : 0.f;
#pragma unroll
  for (int off = 1; off < 32; off <<= 1) s += __shfl_xor(s, off);
  if (t == 0) out[0] = s * (1.0f / TB_);
}

// ---------------------------------------------------------------------------
extern "C" void kernel_launch(void* const* d_in, const int* in_sizes, int n_in,
                              void* d_out, int out_size, void* d_ws, size_t ws_size,
                              hipStream_t stream) {
  const float* e1 = (const float*)d_in[0];
  const float* e2 = (const float*)d_in[1];
  float* out = (float*)d_out;
  char*  E8  = (char*)d_ws;                                       // 4 MB i8
  float* P   = (float*)((char*)d_ws + (size_t)TB_ * D_);          // 2 MB partials
  float* pos = P + (size_t)NTILE * NTILE * BM;                    // 16 KB
  float* par = pos + B_;                                          // 128 B

  ntx_prep<<<1024, 256, 0, stream>>>(e1, e2, E8);
  ntx_sim<<<NTRI, 1024, 0, stream>>>(E8, P, pos);
  ntx_fin1<<<TB_ / 256, 256, 0, stream>>>(P, pos, par);
  ntx_fin2<<<1, 64, 0, stream>>>(par, out);
}

// Round 15
// 55.248 us; speedup vs baseline: 1.0568x; 1.0568x over previous
//
#include <hip/hip_runtime.h>
#include <hip/hip_bf16.h>

#define B_    4096
#define D_    512         // elements = bytes per row (i8)
#define TB_   8192        // 2B rows
#define BM    256         // block tile 256x256
#define BK    128         // 128 B per row per K-tile (0-conflict geometry)
#define NK    4           // D_/BK
#define NT    32          // TB_/BM
#define NTRI  528         // NT*(NT+1)/2 = 8*66 (XCD-bijective)
#define INV_T 14.285714285714286f   // 1/0.07
#define SCL   (INV_T / 16129.0f)    // 1/(0.07*127*127)

typedef __attribute__((ext_vector_type(4))) int v4i;

#define GLOAD_LDS16(gp, lp)                                                        \
  __builtin_amdgcn_global_load_lds((const __attribute__((address_space(1))) void*)(gp), \
                                   (__attribute__((address_space(3))) void*)(lp),  \
                                   16, 0, 0)

// ---------------------------------------------------------------------------
// Kernel 1: concat + quantize fp32 -> int8 (E8[8192][512], q = rn(127 x)).
// ---------------------------------------------------------------------------
__global__ void ntx_prep(const float* __restrict__ a, const float* __restrict__ b,
                         char* __restrict__ E8) {
  int t = blockIdx.x * blockDim.x + threadIdx.x;      // 0..262143
  int i = t * 16;
  const float* src = (i < B_ * D_) ? (a + i) : (b + (i - B_ * D_));
  v4i o;
#pragma unroll
  for (int g = 0; g < 4; ++g) {
    float4 v = ((const float4*)src)[g];
    int q0 = __float2int_rn(v.x * 127.0f) & 255;
    int q1 = __float2int_rn(v.y * 127.0f) & 255;
    int q2 = __float2int_rn(v.z * 127.0f) & 255;
    int q3 = __float2int_rn(v.w * 127.0f) & 255;
    o[g] = q0 | (q1 << 8) | (q2 << 16) | (q3 << 24);
  }
  ((v4i*)E8)[t] = o;
}

// ---------------------------------------------------------------------------
// Kernel 2: 256x256 i8 tile, 16 waves (4x4 grid of 64x64 per wave — R13's
// proven LDS ratio), BK=128, simple 2-barrier loop. 528 blocks ~ 2.06
// rounds at 1 block/CU (16 waves, ~120 unified regs, LDS 64 KB).
// Chunk-XOR swizzle (chunk ^= row&7) on BOTH source and ds_read.
// Epilogue: __expf; per-wave row/col partials -> cross-wave LDS reduce
// (R14-verified) -> single-writer P[ti][tj][256] stores.
// Triangular tiles; off-diag stores mirror col-sums; pos tiles tj==ti+16.
// ---------------------------------------------------------------------------
__global__ __launch_bounds__(1024, 4)
void ntx_sim(const char* __restrict__ E8, float* __restrict__ P,
             float* __restrict__ pos) {
  __shared__ __align__(16) char As[BM * BK];   // 32 KB
  __shared__ __align__(16) char Bs[BM * BK];   // 32 KB

  // XCD-contiguous bijective swizzle (528 = 8*66)
  const int bid = blockIdx.x;
  const int t   = (bid & 7) * (NTRI / 8) + (bid >> 3);
  // decode triangular index t -> (ti, tj), ti<=tj; f(ti) = ti*(65-ti)/2
  int ti = (int)((65.0f - sqrtf(4225.0f - 8.0f * (float)t)) * 0.5f);
  while (ti * (65 - ti) / 2 > t) --ti;
  while ((ti + 1) * (64 - ti) / 2 <= t) ++ti;
  const int tj = ti + (t - ti * (65 - ti) / 2);
  const int rowTile = ti * BM, colTile = tj * BM;
  const bool diag = (ti == tj);
  const bool posT = (tj == ti + B_ / BM);   // holds s[r][r+B] on local diag

  const int tid = threadIdx.x, lane = tid & 63, wave = tid >> 6;
  const int wr = wave >> 2;          // 0..3: 64-row band
  const int wc = wave & 3;           // 0..3: 64-col band
  const int llo = lane & 15, lhi = lane >> 4;

  // staging: tile = 256 rows x 8 chunks(16B) = 2048 chunks; 2/thread/matrix.
  // source pre-swizzled (chunk ^= row&7), LDS linear (both-sides rule #21)
  unsigned offA[2], offB[2], ldsOf[2];
#pragma unroll
  for (int r = 0; r < 2; ++r) {
    int ch = r * 1024 + tid, row = ch >> 3;
    int sc = ((ch & 7) ^ (row & 7)) << 4;           // byte offset in row
    offA[r]  = (unsigned)(rowTile + row) * D_ + sc;
    offB[r]  = (unsigned)(colTile + row) * D_ + sc;
    ldsOf[r] = (unsigned)ch * 16;
  }
  // fragment byte-offsets (same involution on read); 16 B per lane per ks
  unsigned fA[2][4], fB[2][4];
#pragma unroll
  for (int ks = 0; ks < 2; ++ks)
#pragma unroll
    for (int m = 0; m < 4; ++m) {
      int chc = ks * 4 + lhi;
      int ra  = wr * 64 + m * 16 + llo;
      fA[ks][m] = (unsigned)(ra * BK + (((unsigned)chc ^ (ra & 7)) << 4));
      int rb  = wc * 64 + m * 16 + llo;
      fB[ks][m] = (unsigned)(rb * BK + (((unsigned)chc ^ (rb & 7)) << 4));
    }

  v4i acc[4][4] = {};

  for (int kt = 0; kt < NK; ++kt) {
    const unsigned kb = (unsigned)kt * BK;
#pragma unroll
    for (int r = 0; r < 2; ++r) GLOAD_LDS16(E8 + offA[r] + kb, &As[ldsOf[r]]);
#pragma unroll
    for (int r = 0; r < 2; ++r) GLOAD_LDS16(E8 + offB[r] + kb, &Bs[ldsOf[r]]);
    __syncthreads();   // drains vmcnt: tile resident
#pragma unroll
    for (int ks = 0; ks < 2; ++ks) {
      v4i af[4], bf[4];
#pragma unroll
      for (int m = 0; m < 4; ++m) {
        af[m] = *(const v4i*)&As[fA[ks][m]];
        bf[m] = *(const v4i*)&Bs[fB[ks][m]];
      }
#pragma unroll
      for (int m = 0; m < 4; ++m)
#pragma unroll
        for (int n = 0; n < 4; ++n)
          acc[m][n] = __builtin_amdgcn_mfma_i32_16x16x64_i8(af[m], bf[n],
                                                            acc[m][n], 0, 0, 0);
    }
    __syncthreads();   // protect LDS before next staging (last: frees LDS)
  }

  // --- epilogue: __expf, per-wave partials, cross-wave LDS reduce ---
  // C/D layout: col = lane&15, row = (lane>>4)*4 + reg
  float* Rbuf = (float*)As;   // [4 wc][256 rows] = 4 KB (LDS reuse post-loop)
  float* Cbuf = (float*)Bs;   // [4 wr][256 cols] = 4 KB
  float cs[4] = {0.f, 0.f, 0.f, 0.f};
#pragma unroll
  for (int m = 0; m < 4; ++m) {
    float rs[4] = {0.f, 0.f, 0.f, 0.f};
#pragma unroll
    for (int n = 0; n < 4; ++n) {
      int gc = colTile + wc * 64 + n * 16 + llo;
#pragma unroll
      for (int jj = 0; jj < 4; ++jj) {
        int gr = rowTile + wr * 64 + m * 16 + lhi * 4 + jj;
        float s = (float)acc[m][n][jj] * SCL;
        if (posT && gc - gr == B_) pos[gr] = s;   // unique writer
        float e = __expf(s);
        e = (diag && gr == gc) ? 0.0f : e;
        rs[jj] += e;
        cs[n]  += e;
      }
    }
#pragma unroll
    for (int jj = 0; jj < 4; ++jj) {
      float v = rs[jj];
      v += __shfl_xor(v, 1);
      v += __shfl_xor(v, 2);
      v += __shfl_xor(v, 4);
      v += __shfl_xor(v, 8);
      if (llo == 0) Rbuf[wc * 256 + wr * 64 + m * 16 + lhi * 4 + jj] = v;
    }
  }
#pragma unroll
  for (int n = 0; n < 4; ++n) {
    float v = cs[n];
    v += __shfl_xor(v, 16);
    v += __shfl_xor(v, 32);
    if (lhi == 0) Cbuf[wr * 256 + wc * 64 + n * 16 + llo] = v;
  }
  __syncthreads();
  if (tid < 256) {
    float v = Rbuf[tid] + Rbuf[256 + tid] + Rbuf[512 + tid] + Rbuf[768 + tid];
    P[((size_t)ti * NT + tj) * BM + tid] = v;             // one writer/slot
  } else if (tid < 512 && !diag) {
    int c = tid - 256;
    float v = Cbuf[c] + Cbuf[256 + c] + Cbuf[512 + c] + Cbuf[768 + c];
    P[((size_t)tj * NT + ti) * BM + c] = v;               // mirror slot
  }
}

// ---------------------------------------------------------------------------
// Kernel 3: gather L[r] = sum_j P[ti][j][rloc]; nll = log(L) - pos;
// per-block partial -> par[32].
// ---------------------------------------------------------------------------
__global__ void ntx_fin1(const float* __restrict__ P, const float* __restrict__ pos,
                         float* __restrict__ par) {
  int r = blockIdx.x * 256 + threadIdx.x;     // 32 blocks x 256 rows
  int ti = r >> 8, rloc = r & 255;
  const float* base = P + (size_t)ti * NT * BM + rloc;
  float s = 0.f;
#pragma unroll 8
  for (int j = 0; j < NT; ++j) s += base[j * BM];
  float nll = __logf(s) - pos[r & (B_ - 1)];
  float v = nll;
#pragma unroll
  for (int off = 1; off < 64; off <<= 1) v += __shfl_xor(v, off);
  __shared__ float sm[4];
  if ((threadIdx.x & 63) == 0) sm[threadIdx.x >> 6] = v;
  __syncthreads();
  if (threadIdx.x == 0) par[blockIdx.x] = sm[0] + sm[1] + sm[2] + sm[3];
}

// Kernel 4: fold 32 partials -> mean
__global__ void ntx_fin2(const float* __restrict__ par, float* __restrict__ out) {
  int t = threadIdx.x;                         // 64 threads
  float s = (t < 32) ? par[t] : 0.f;
#pragma unroll
  for (int off = 1; off < 32; off <<= 1) s += __shfl_xor(s, off);
  if (t == 0) out[0] = s * (1.0f / TB_);
}

// ---------------------------------------------------------------------------
extern "C" void kernel_launch(void* const* d_in, const int* in_sizes, int n_in,
                              void* d_out, int out_size, void* d_ws, size_t ws_size,
                              hipStream_t stream) {
  const float* e1 = (const float*)d_in[0];
  const float* e2 = (const float*)d_in[1];
  float* out = (float*)d_out;
  char*  E8  = (char*)d_ws;                                       // 4 MB i8
  float* P   = (float*)((char*)d_ws + (size_t)TB_ * D_);          // 1 MB partials
  float* pos = P + (size_t)NT * NT * BM;                          // 16 KB
  float* par = pos + B_;                                          // 128 B

  ntx_prep<<<1024, 256, 0, stream>>>(e1, e2, E8);
  ntx_sim<<<NTRI, 1024, 0, stream>>>(E8, P, pos);
  ntx_fin1<<<TB_ / 256, 256, 0, stream>>>(P, pos, par);
  ntx_fin2<<<1, 64, 0, stream>>>(par, out);
}